// Round 4
// baseline (682.745 us; speedup 1.0000x reference)
//
#include <hip/hip_runtime.h>
#include <type_traits>

// Problem constants: H=16, D=64, DM=1024, L=256, B=64, CHUNK=64, SCALE=1/8.

typedef short v8s __attribute__((ext_vector_type(8)));
typedef float v4f __attribute__((ext_vector_type(4)));

__device__ __forceinline__ float bf2f(short s) {
    unsigned int u = ((unsigned int)(unsigned short)s) << 16;
    float f;
    __builtin_memcpy(&f, &u, 4);
    return f;
}
__device__ __forceinline__ short f2bf(float f) {
    unsigned int u;
    __builtin_memcpy(&u, &f, 4);
    u = u + 0x7fffu + ((u >> 16) & 1u);   // RNE
    return (short)(u >> 16);
}

// async global->LDS, 16B per lane; LDS dest = wave-uniform base + lane*16
__device__ __forceinline__ void load_lds16(const short* g, short* l) {
    __builtin_amdgcn_global_load_lds((const __attribute__((address_space(1))) void*)g,
                                     (__attribute__((address_space(3))) void*)l, 16, 0, 0);
}

// ---------------- fp32 -> bf16 conversion (vectorized x4) ----------------
__global__ void __launch_bounds__(256)
cvt_bf16(const float* __restrict__ in, short* __restrict__ out, int n4) {
    int i = blockIdx.x * 256 + threadIdx.x;
    if (i >= n4) return;
    float4 v = ((const float4*)in)[i];
    short4 o;
    o.x = f2bf(v.x); o.y = f2bf(v.y); o.z = f2bf(v.z); o.w = f2bf(v.w);
    ((short4*)out)[i] = o;
}

// ---------------- bf16 MFMA GEMM:  C[M,N] = A[M,K] * B[N,K]^T ----------------
// 256x256 tile, BK=64, 8 waves (2Mx4N), 512 threads, 8-phase counted-vmcnt
// schedule (verified R1/R2) + L2-compact per-XCD block mapping (verified R3:
// FETCH 287->106MB). Unchanged from R3.
template <typename OutT>
__global__ void __launch_bounds__(512, 2)
gemm_nt(const short* __restrict__ Ap, const short* __restrict__ Bp,
        OutT* __restrict__ C, int M, int N, int K) {
    __shared__ __align__(16) short lds[2][2][256 * 64];

    const int tid = threadIdx.x;
    const int w = tid >> 6, lane = tid & 63;
    const int wm = w >> 2, wn = w & 3;
    const int lq = lane >> 4, lr = lane & 15;
    const int asw = (lr & 7) * 8;
    const int rr = tid >> 3;
    const int scol = ((tid & 7) * 8) ^ ((rr & 7) * 8);

    int bid = blockIdx.y * gridDim.x + blockIdx.x;
    int bm, bn;
    if (gridDim.x == 64) {
        int xcd = bid & 7, u = bid >> 3;
        bm = xcd * 8 + (u & 7);
        bn = u >> 3;
    } else {
        int nwg = gridDim.x * gridDim.y;
        int swz = (bid & 7) * (nwg >> 3) + (bid >> 3);
        bm = swz % gridDim.x; bn = swz / gridDim.x;
    }

    v4f acc[8][4] = {};
    v8s a[4][2];
    v8s b[2][2][2];

    const int NT = K >> 6;
    const int nIter = NT >> 1;

#define BAR_() do { asm volatile("" ::: "memory"); __builtin_amdgcn_s_barrier(); asm volatile("" ::: "memory"); } while (0)
#define SBAR_() __builtin_amdgcn_sched_barrier(0)
#define VMCNT4_() asm volatile("s_waitcnt vmcnt(4)" ::: "memory")
#define STAGE_(MAT, BUF, HALF, KT) do { \
        const short* g_ = ((MAT) ? Bp : Ap) + \
            (long)(((MAT) ? bn : bm) * 256 + (HALF) * 128 + rr) * K + (KT) * 64 + scol; \
        short* l_ = &lds[BUF][MAT][(HALF) * 8192] + w * 512; \
        load_lds16(g_, l_); \
        load_lds16(g_ + (long)64 * K, l_ + 4096); \
    } while (0)
#define LDA_(QM, BUF) do { \
        _Pragma("unroll") \
        for (int mi = 0; mi < 4; ++mi) { \
            const short* pa_ = &lds[BUF][0][(wm * 128 + (QM) * 64 + mi * 16 + lr) * 64]; \
            a[mi][0] = *(const v8s*)&pa_[(lq * 8) ^ asw]; \
            a[mi][1] = *(const v8s*)&pa_[(32 + lq * 8) ^ asw]; \
        } \
    } while (0)
#define LDB_(QN, BUF) do { \
        _Pragma("unroll") \
        for (int ni = 0; ni < 2; ++ni) { \
            const short* pb_ = &lds[BUF][1][(wn * 64 + (QN) * 32 + ni * 16 + lr) * 64]; \
            b[QN][ni][0] = *(const v8s*)&pb_[(lq * 8) ^ asw]; \
            b[QN][ni][1] = *(const v8s*)&pb_[(32 + lq * 8) ^ asw]; \
        } \
    } while (0)
#define MFMA_(QM, QN) do { \
        __builtin_amdgcn_s_setprio(1); \
        _Pragma("unroll") \
        for (int kk = 0; kk < 2; ++kk) \
            _Pragma("unroll") \
            for (int mi = 0; mi < 4; ++mi) \
                _Pragma("unroll") \
                for (int ni = 0; ni < 2; ++ni) \
                    acc[(QM) * 4 + mi][(QN) * 2 + ni] = __builtin_amdgcn_mfma_f32_16x16x32_bf16( \
                        a[mi][kk], b[QN][ni][kk], acc[(QM) * 4 + mi][(QN) * 2 + ni], 0, 0, 0); \
        __builtin_amdgcn_s_setprio(0); \
    } while (0)

    STAGE_(1, 0, 0, 0);
    STAGE_(1, 0, 1, 0);
    STAGE_(0, 0, 0, 0);
    STAGE_(0, 0, 1, 0);
    STAGE_(1, 1, 0, 1);
    STAGE_(1, 1, 1, 1);
    VMCNT4_();
    BAR_();

    for (int it = 0; it < nIter; ++it) {
        const int t1 = 2 * it + 1;
        int t2 = 2 * it + 2; if (t2 >= NT) t2 -= NT;
        int t3 = 2 * it + 3; if (t3 >= NT) t3 -= NT;

        LDA_(0, 0); LDB_(0, 0); LDB_(1, 0);
        STAGE_(0, 1, 0, t1);
        MFMA_(0, 0);
        SBAR_(); BAR_();
        STAGE_(0, 1, 1, t1);
        MFMA_(0, 1);
        SBAR_();
        LDA_(1, 0);
        SBAR_(); BAR_();
        STAGE_(1, 0, 0, t2);
        MFMA_(1, 0);
        SBAR_(); BAR_();
        STAGE_(1, 0, 1, t2);
        VMCNT4_();
        MFMA_(1, 1);
        SBAR_(); BAR_();
        LDA_(0, 1); LDB_(0, 1); LDB_(1, 1);
        STAGE_(0, 0, 0, t2);
        MFMA_(0, 0);
        SBAR_(); BAR_();
        STAGE_(0, 0, 1, t2);
        MFMA_(0, 1);
        SBAR_();
        LDA_(1, 1);
        SBAR_(); BAR_();
        STAGE_(1, 1, 0, t3);
        MFMA_(1, 0);
        SBAR_(); BAR_();
        STAGE_(1, 1, 1, t3);
        VMCNT4_();
        MFMA_(1, 1);
        SBAR_(); BAR_();
    }

#undef BAR_
#undef SBAR_
#undef VMCNT4_
#undef STAGE_
#undef LDA_
#undef LDB_
#undef MFMA_

#pragma unroll
    for (int m = 0; m < 8; ++m)
#pragma unroll
        for (int n = 0; n < 4; ++n)
#pragma unroll
            for (int r = 0; r < 4; ++r) {
                int row = bm * 256 + wm * 128 + m * 16 + lq * 4 + r;
                int col = bn * 256 + wn * 64 + n * 16 + lr;
                float v = acc[m][n][r];
                if constexpr (std::is_same_v<OutT, short>)
                    C[(long)row * N + col] = f2bf(v);
                else
                    C[(long)row * N + col] = v;
            }
}

// ---------------- fast-weight scan: 2-wave blocks, one memory per wave ----------------
// One (b,h) per 128-thread block. wave0 = mem1, wave1 = mem2. Shared LDS areas:
// Aq (q rows -> W1^T), Av (v^T -> o2 exchange); private: Ak1 (k1->S1),
// Ak2 (k2->S2), Aw2 (W2^T). 40KB -> 4 blocks/CU (8 independent waves).
// phi is lane-local (lane=row). W^T state lives in 64 f32 accumulator regs/wave.
// All LDS XOR-swizzled; staging via global_load_lds with pre-swizzled source.
#define SZF(row, col) (((row) << 6) + ((col) ^ (((row) & 7) << 3)))
#define LGKM0_() do { asm volatile("s_waitcnt lgkmcnt(0)" ::: "memory"); __builtin_amdgcn_sched_barrier(0); } while (0)

__global__ void __launch_bounds__(128, 2)
fastweight(const short* __restrict__ qkv, const float* __restrict__ pi0,
           short* __restrict__ outm) {
    const int bid = blockIdx.x;
    const int h = bid & 15, b = bid >> 4;
    const int tid = threadIdx.x;
    const int wv = tid >> 6, lane = tid & 63;
    const int lq = lane >> 4, lr = lane & 15;

    __shared__ __align__(16) short Aq[4096];
    __shared__ __align__(16) short Ak1[4096];
    __shared__ __align__(16) short Ak2[4096];
    __shared__ __align__(16) short Av[4096];
    __shared__ __align__(16) short Aw2[4096];

    short* const Akm = wv ? Ak2 : Ak1;
    short* const Awm = wv ? Aw2 : Aq;

    const int srow = lane >> 3;                          // staging row-in-8 group
    const int scolw = ((lane & 7) ^ (srow & 7)) << 3;    // pre-swizzled src col (shorts)
    const long LSTR = 64L * 4096;                        // shorts per l step

    // stage one 64x64 bf16 matrix into an LDS area (8 x global_load_lds 16B)
    auto stage_mat = [&](int c, int mat, short* area) {
        const short* g = qkv + ((long)((c * 64 + srow) * 64 + b)) * 4096 + h * 256 + mat * 64 + scolw;
#pragma unroll
        for (int i = 0; i < 8; i++)
            load_lds16(g + (long)i * 8 * LSTR, area + i * 512);
    };

    // phi (elu+1, row-normalize) in place; lane = row, fully lane-local.
    auto phi_inplace = [&](short* area) {
        v8s r[8];
#pragma unroll
        for (int g = 0; g < 8; g++)
            r[g] = *(const v8s*)&area[SZF(lane, g * 8)];
        float e[64];
        float s = 0.f;
#pragma unroll
        for (int g = 0; g < 8; g++)
#pragma unroll
            for (int k = 0; k < 8; k++) {
                float x = bf2f(r[g][k]);
                float v = x > 0.f ? x + 1.f : __expf(x);
                e[g * 8 + k] = v; s += v;
            }
        float inv = 1.f / s;
#pragma unroll
        for (int g = 0; g < 8; g++) {
            v8s o;
#pragma unroll
            for (int k = 0; k < 8; k++) o[k] = f2bf(e[g * 8 + k] * inv);
            *(v8s*)&area[SZF(lane, g * 8)] = o;
        }
    };

    // in-place transpose (lane reads its row, all lanes then scatter columns)
    auto transpose_inplace = [&](short* area) {
        v8s r[8];
#pragma unroll
        for (int g = 0; g < 8; g++)
            r[g] = *(const v8s*)&area[SZF(lane, g * 8)];
        LGKM0_();   // all lanes' reads complete before any scatter write
#pragma unroll
        for (int g = 0; g < 8; g++)
#pragma unroll
            for (int k = 0; k < 8; k++)
                area[SZF(g * 8 + k, lane)] = r[g][k];
    };

    v4f wacc[4][4] = {};   // W^T state: (d_out tile i, d_in tile n), C-layout

    // prologue: stage chunk 0
    if (wv == 0) { stage_mat(0, 0, Aq); stage_mat(0, 1, Ak1); }
    else         { stage_mat(0, 3, Av); stage_mat(0, 2, Ak2); }

    for (int c = 0; c < 4; c++) {
        __syncthreads();   // B1: staged raw visible (drains vmcnt + lgkm)

        if (wv == 0) { phi_inplace(Aq); phi_inplace(Ak1); }
        else         { transpose_inplace(Av); phi_inplace(Ak2); }
        __syncthreads();   // B2: Aq/Av/Ak ready for cross-wave frag reads

        // fragment reads (A-frag and B-frag share the same lane->data pattern)
        v8s qa[4][2], vf[4][2], kb[4][2], ktb[4][2];
#pragma unroll
        for (int i = 0; i < 4; i++)
#pragma unroll
            for (int kk = 0; kk < 2; kk++) {
                qa[i][kk] = *(const v8s*)&Aq[SZF(16 * i + lr, 32 * kk + 8 * lq)];
                vf[i][kk] = *(const v8s*)&Av[SZF(16 * i + lr, 32 * kk + 8 * lq)];
                kb[i][kk] = *(const v8s*)&Akm[SZF(16 * i + lr, 32 * kk + 8 * lq)];
            }
        if (c < 3) {   // k^T B-frags for dW (column gather, scalar reads)
#pragma unroll
            for (int j = 0; j < 4; j++)
#pragma unroll
                for (int kk = 0; kk < 2; kk++) {
                    v8s t;
#pragma unroll
                    for (int e = 0; e < 8; e++)
                        t[e] = Akm[SZF(32 * kk + 8 * lq + e, 16 * j + lr)];
                    ktb[j][kk] = t;
                }
        }

        // pi0 rows for this chunk (wave0 only; lands under MFMA, drained by B4)
        float pv[4][4];
        if (wv == 0) {
#pragma unroll
            for (int i = 0; i < 4; i++)
#pragma unroll
                for (int r2 = 0; r2 < 4; r2++) {
                    float p = pi0[h * 256 + c * 64 + 16 * i + lq * 4 + r2];
                    pv[i][r2] = fminf(fmaxf(p, 0.f), 1.f);
                }
        }

        // S = q k^T, causal mask, pack bf16
        unsigned int spk[4][4][2];
#pragma unroll
        for (int i = 0; i < 4; i++)
#pragma unroll
            for (int n = 0; n < 4; n++) {
                v4f t = {};
                t = __builtin_amdgcn_mfma_f32_16x16x32_bf16(qa[i][0], kb[n][0], t, 0, 0, 0);
                t = __builtin_amdgcn_mfma_f32_16x16x32_bf16(qa[i][1], kb[n][1], t, 0, 0, 0);
                unsigned int pk[2] = {0u, 0u};
#pragma unroll
                for (int r2 = 0; r2 < 4; r2++) {
                    int t_ = 16 * i + lq * 4 + r2;
                    int s_ = 16 * n + lr;
                    unsigned int bv = (unsigned int)(unsigned short)f2bf(s_ <= t_ ? t[r2] : 0.f);
                    pk[r2 >> 1] |= bv << (16 * (r2 & 1));
                }
                spk[i][n][0] = pk[0]; spk[i][n][1] = pk[1];
            }

        __syncthreads();   // B3: all frag reads done; Aq/Ak areas overwritable

        // W^T_pre -> LDS (for O's QW B-frags), before the dW update
        if (c > 0) {
#pragma unroll
            for (int i = 0; i < 4; i++)
#pragma unroll
                for (int n = 0; n < 4; n++)
#pragma unroll
                    for (int r2 = 0; r2 < 4; r2++)
                        Awm[SZF(16 * i + lq * 4 + r2, 16 * n + lr)] = f2bf(wacc[i][n][r2]);
        }
        // dW^T = v^T k (accumulate into register state)
        if (c < 3) {
#pragma unroll
            for (int i = 0; i < 4; i++)
#pragma unroll
                for (int n = 0; n < 4; n++) {
                    wacc[i][n] = __builtin_amdgcn_mfma_f32_16x16x32_bf16(vf[i][0], ktb[n][0], wacc[i][n], 0, 0, 0);
                    wacc[i][n] = __builtin_amdgcn_mfma_f32_16x16x32_bf16(vf[i][1], ktb[n][1], wacc[i][n], 0, 0, 0);
                }
        }
        // S -> LDS (own k area)
#pragma unroll
        for (int i = 0; i < 4; i++)
#pragma unroll
            for (int n = 0; n < 4; n++)
#pragma unroll
                for (int r2 = 0; r2 < 4; r2++)
                    Akm[SZF(16 * i + lq * 4 + r2, 16 * n + lr)] =
                        (short)(spk[i][n][r2 >> 1] >> (16 * (r2 & 1)));

        LGKM0_();   // own-wave S/W writes complete before own frag reads

        v8s sa[4][2], wb[4][2];
#pragma unroll
        for (int i = 0; i < 4; i++)
#pragma unroll
            for (int kk = 0; kk < 2; kk++) {
                sa[i][kk] = *(const v8s*)&Akm[SZF(16 * i + lr, 32 * kk + 8 * lq)];
                if (c > 0)
                    wb[i][kk] = *(const v8s*)&Awm[SZF(16 * i + lr, 32 * kk + 8 * lq)];
            }

        // O = S v + q W_pre, pack bf16
        unsigned int opk[4][4][2];
#pragma unroll
        for (int i = 0; i < 4; i++)
#pragma unroll
            for (int j = 0; j < 4; j++) {
                v4f t = {};
                t = __builtin_amdgcn_mfma_f32_16x16x32_bf16(sa[i][0], vf[j][0], t, 0, 0, 0);
                t = __builtin_amdgcn_mfma_f32_16x16x32_bf16(sa[i][1], vf[j][1], t, 0, 0, 0);
                if (c > 0) {
                    t = __builtin_amdgcn_mfma_f32_16x16x32_bf16(qa[i][0], wb[j][0], t, 0, 0, 0);
                    t = __builtin_amdgcn_mfma_f32_16x16x32_bf16(qa[i][1], wb[j][1], t, 0, 0, 0);
                }
                unsigned int pk[2] = {0u, 0u};
#pragma unroll
                for (int r2 = 0; r2 < 4; r2++) {
                    unsigned int bv = (unsigned int)(unsigned short)f2bf(t[r2]);
                    pk[r2 >> 1] |= bv << (16 * (r2 & 1));
                }
                opk[i][j][0] = pk[0]; opk[i][j][1] = pk[1];
            }

        // wave1 publishes o2 (bf16) through the freed Av area
        if (wv == 1) {
#pragma unroll
            for (int i = 0; i < 4; i++)
#pragma unroll
                for (int j = 0; j < 4; j++)
#pragma unroll
                    for (int r2 = 0; r2 < 4; r2++)
                        Av[SZF(16 * i + lq * 4 + r2, 16 * j + lr)] =
                            (short)(opk[i][j][r2 >> 1] >> (16 * (r2 & 1)));
        }
        __syncthreads();   // B4: o2 visible

        if (wv == 0) {
            // mix + store
#pragma unroll
            for (int i = 0; i < 4; i++)
#pragma unroll
                for (int j = 0; j < 4; j++)
#pragma unroll
                    for (int r2 = 0; r2 < 4; r2++) {
                        int t_ = 16 * i + lq * 4 + r2;
                        float o1 = bf2f((short)(opk[i][j][r2 >> 1] >> (16 * (r2 & 1))));
                        float o2 = bf2f(Av[SZF(t_, 16 * j + lr)]);
                        float p = pv[i][r2];
                        float val = 0.125f * (p * o1 + (1.f - p) * o2);
                        outm[((long)((c * 64 + t_) * 64 + b)) * 1024 + h * 64 + 16 * j + lr] = f2bf(val);
                    }
        } else if (c < 3) {
            stage_mat(c + 1, 2, Ak2);   // private area, safe now
        }
        __syncthreads();   // B5: wave0's o2 reads done; Av free

        if (c < 3) {
            if (wv == 0) { stage_mat(c + 1, 0, Aq); stage_mat(c + 1, 1, Ak1); }
            else         { stage_mat(c + 1, 3, Av); }
        }
    }
}

// ---------------- residual + LayerNorm over DM=1024 ----------------
__global__ void __launch_bounds__(256)
ln_kernel(const float* __restrict__ h, const float* __restrict__ attn,
          const float* __restrict__ gamma, const float* __restrict__ beta,
          float* __restrict__ out) {
    const int row = blockIdx.x;
    const long base = (long)row * 1024;
    const int tid = threadIdx.x;
    float4 xh = ((const float4*)(h + base))[tid];
    float4 xa = ((const float4*)(attn + base))[tid];
    float4 x;
    x.x = xh.x + xa.x; x.y = xh.y + xa.y; x.z = xh.z + xa.z; x.w = xh.w + xa.w;
    float s = x.x + x.y + x.z + x.w;
    float s2 = x.x * x.x + x.y * x.y + x.z * x.z + x.w * x.w;
#pragma unroll
    for (int m = 32; m > 0; m >>= 1) {
        s += __shfl_xor(s, m, 64);
        s2 += __shfl_xor(s2, m, 64);
    }
    __shared__ float ps[4], ps2[4];
    int w = tid >> 6, lane = tid & 63;
    if (lane == 0) { ps[w] = s; ps2[w] = s2; }
    __syncthreads();
    s = ps[0] + ps[1] + ps[2] + ps[3];
    s2 = ps2[0] + ps2[1] + ps2[2] + ps2[3];
    float mu = s * (1.f / 1024.f);
    float var = s2 * (1.f / 1024.f) - mu * mu;
    float inv = rsqrtf(var + 1e-5f);
    float4 g = ((const float4*)gamma)[tid];
    float4 bb = ((const float4*)beta)[tid];
    float4 o;
    o.x = (x.x - mu) * inv * g.x + bb.x;
    o.y = (x.y - mu) * inv * g.y + bb.y;
    o.z = (x.z - mu) * inv * g.z + bb.z;
    o.w = (x.w - mu) * inv * g.w + bb.w;
    ((float4*)(out + base))[tid] = o;
}

extern "C" void kernel_launch(void* const* d_in, const int* in_sizes, int n_in,
                              void* d_out, int out_size, void* d_ws, size_t ws_size,
                              hipStream_t stream) {
    const float* h     = (const float*)d_in[0];
    const float* qkvw  = (const float*)d_in[1];
    const float* ow    = (const float*)d_in[2];
    const float* gamma = (const float*)d_in[3];
    const float* beta  = (const float*)d_in[4];
    const float* pi0   = (const float*)d_in[5];
    float* out = (float*)d_out;
    char* ws = (char*)d_ws;

    short* h_bf   = (short*)(ws);                 // 32MB; reused later as lmix
    short* wq_bf  = (short*)(ws + 33554432);      // 8MB
    short* wo_bf  = (short*)(ws + 41943040);      // 2MB
    short* qkv_bf = (short*)(ws + 44040192);      // 128MB; reused later as attn f32 (64MB)
    float* attnf  = (float*)(ws + 44040192);
    short* lmix   = h_bf;

    cvt_bf16<<<16384, 256, 0, stream>>>(h, h_bf, 16777216 / 4);
    cvt_bf16<<<4096, 256, 0, stream>>>(qkvw, wq_bf, 4194304 / 4);
    cvt_bf16<<<1024, 256, 0, stream>>>(ow, wo_bf, 1048576 / 4);

    gemm_nt<short><<<dim3(64, 16), 512, 0, stream>>>(h_bf, wq_bf, qkv_bf, 16384, 4096, 1024);

    fastweight<<<1024, 128, 0, stream>>>(qkv_bf, pi0, lmix);

    gemm_nt<float><<<dim3(64, 4), 512, 0, stream>>>(lmix, wo_bf, attnf, 16384, 1024, 1024);

    ln_kernel<<<16384, 256, 0, stream>>>(h, attnf, gamma, beta, out);
}

// Round 5
// 412.020 us; speedup vs baseline: 1.6571x; 1.6571x over previous
//
#include <hip/hip_runtime.h>
#include <type_traits>

// Problem constants: H=16, D=64, DM=1024, L=256, B=64, CHUNK=64, SCALE=1/8.

typedef short v8s __attribute__((ext_vector_type(8)));
typedef float v4f __attribute__((ext_vector_type(4)));

__device__ __forceinline__ float bf2f(short s) {
    unsigned int u = ((unsigned int)(unsigned short)s) << 16;
    float f;
    __builtin_memcpy(&f, &u, 4);
    return f;
}
__device__ __forceinline__ short f2bf(float f) {
    unsigned int u;
    __builtin_memcpy(&u, &f, 4);
    u = u + 0x7fffu + ((u >> 16) & 1u);   // RNE
    return (short)(u >> 16);
}

// async global->LDS, 16B per lane; LDS dest = wave-uniform base + lane*16
__device__ __forceinline__ void load_lds16(const short* g, short* l) {
    __builtin_amdgcn_global_load_lds((const __attribute__((address_space(1))) void*)g,
                                     (__attribute__((address_space(3))) void*)l, 16, 0, 0);
}

// ---------------- fp32 -> bf16 conversion (vectorized x4) ----------------
__global__ void __launch_bounds__(256)
cvt_bf16(const float* __restrict__ in, short* __restrict__ out, int n4) {
    int i = blockIdx.x * 256 + threadIdx.x;
    if (i >= n4) return;
    float4 v = ((const float4*)in)[i];
    short4 o;
    o.x = f2bf(v.x); o.y = f2bf(v.y); o.z = f2bf(v.z); o.w = f2bf(v.w);
    ((short4*)out)[i] = o;
}

// ---------------- bf16 MFMA GEMM:  C[M,N] = A[M,K] * B[N,K]^T ----------------
// 256x256 tile, BK=64, 8 waves (2Mx4N), 512 threads, 8-phase counted-vmcnt
// schedule + L2-compact per-XCD block mapping (verified R3: FETCH 287->106MB).
// Unchanged from R3/R4.
template <typename OutT>
__global__ void __launch_bounds__(512, 2)
gemm_nt(const short* __restrict__ Ap, const short* __restrict__ Bp,
        OutT* __restrict__ C, int M, int N, int K) {
    __shared__ __align__(16) short lds[2][2][256 * 64];

    const int tid = threadIdx.x;
    const int w = tid >> 6, lane = tid & 63;
    const int wm = w >> 2, wn = w & 3;
    const int lq = lane >> 4, lr = lane & 15;
    const int asw = (lr & 7) * 8;
    const int rr = tid >> 3;
    const int scol = ((tid & 7) * 8) ^ ((rr & 7) * 8);

    int bid = blockIdx.y * gridDim.x + blockIdx.x;
    int bm, bn;
    if (gridDim.x == 64) {
        int xcd = bid & 7, u = bid >> 3;
        bm = xcd * 8 + (u & 7);
        bn = u >> 3;
    } else {
        int nwg = gridDim.x * gridDim.y;
        int swz = (bid & 7) * (nwg >> 3) + (bid >> 3);
        bm = swz % gridDim.x; bn = swz / gridDim.x;
    }

    v4f acc[8][4] = {};
    v8s a[4][2];
    v8s b[2][2][2];

    const int NT = K >> 6;
    const int nIter = NT >> 1;

#define BAR_() do { asm volatile("" ::: "memory"); __builtin_amdgcn_s_barrier(); asm volatile("" ::: "memory"); } while (0)
#define SBAR_() __builtin_amdgcn_sched_barrier(0)
#define VMCNT4_() asm volatile("s_waitcnt vmcnt(4)" ::: "memory")
#define STAGE_(MAT, BUF, HALF, KT) do { \
        const short* g_ = ((MAT) ? Bp : Ap) + \
            (long)(((MAT) ? bn : bm) * 256 + (HALF) * 128 + rr) * K + (KT) * 64 + scol; \
        short* l_ = &lds[BUF][MAT][(HALF) * 8192] + w * 512; \
        load_lds16(g_, l_); \
        load_lds16(g_ + (long)64 * K, l_ + 4096); \
    } while (0)
#define LDA_(QM, BUF) do { \
        _Pragma("unroll") \
        for (int mi = 0; mi < 4; ++mi) { \
            const short* pa_ = &lds[BUF][0][(wm * 128 + (QM) * 64 + mi * 16 + lr) * 64]; \
            a[mi][0] = *(const v8s*)&pa_[(lq * 8) ^ asw]; \
            a[mi][1] = *(const v8s*)&pa_[(32 + lq * 8) ^ asw]; \
        } \
    } while (0)
#define LDB_(QN, BUF) do { \
        _Pragma("unroll") \
        for (int ni = 0; ni < 2; ++ni) { \
            const short* pb_ = &lds[BUF][1][(wn * 64 + (QN) * 32 + ni * 16 + lr) * 64]; \
            b[QN][ni][0] = *(const v8s*)&pb_[(lq * 8) ^ asw]; \
            b[QN][ni][1] = *(const v8s*)&pb_[(32 + lq * 8) ^ asw]; \
        } \
    } while (0)
#define MFMA_(QM, QN) do { \
        __builtin_amdgcn_s_setprio(1); \
        _Pragma("unroll") \
        for (int kk = 0; kk < 2; ++kk) \
            _Pragma("unroll") \
            for (int mi = 0; mi < 4; ++mi) \
                _Pragma("unroll") \
                for (int ni = 0; ni < 2; ++ni) \
                    acc[(QM) * 4 + mi][(QN) * 2 + ni] = __builtin_amdgcn_mfma_f32_16x16x32_bf16( \
                        a[mi][kk], b[QN][ni][kk], acc[(QM) * 4 + mi][(QN) * 2 + ni], 0, 0, 0); \
        __builtin_amdgcn_s_setprio(0); \
    } while (0)

    STAGE_(1, 0, 0, 0);
    STAGE_(1, 0, 1, 0);
    STAGE_(0, 0, 0, 0);
    STAGE_(0, 0, 1, 0);
    STAGE_(1, 1, 0, 1);
    STAGE_(1, 1, 1, 1);
    VMCNT4_();
    BAR_();

    for (int it = 0; it < nIter; ++it) {
        const int t1 = 2 * it + 1;
        int t2 = 2 * it + 2; if (t2 >= NT) t2 -= NT;
        int t3 = 2 * it + 3; if (t3 >= NT) t3 -= NT;

        LDA_(0, 0); LDB_(0, 0); LDB_(1, 0);
        STAGE_(0, 1, 0, t1);
        MFMA_(0, 0);
        SBAR_(); BAR_();
        STAGE_(0, 1, 1, t1);
        MFMA_(0, 1);
        SBAR_();
        LDA_(1, 0);
        SBAR_(); BAR_();
        STAGE_(1, 0, 0, t2);
        MFMA_(1, 0);
        SBAR_(); BAR_();
        STAGE_(1, 0, 1, t2);
        VMCNT4_();
        MFMA_(1, 1);
        SBAR_(); BAR_();
        LDA_(0, 1); LDB_(0, 1); LDB_(1, 1);
        STAGE_(0, 0, 0, t2);
        MFMA_(0, 0);
        SBAR_(); BAR_();
        STAGE_(0, 0, 1, t2);
        MFMA_(0, 1);
        SBAR_();
        LDA_(1, 1);
        SBAR_(); BAR_();
        STAGE_(1, 1, 0, t3);
        MFMA_(1, 0);
        SBAR_(); BAR_();
        STAGE_(1, 1, 1, t3);
        VMCNT4_();
        MFMA_(1, 1);
        SBAR_(); BAR_();
    }

#undef BAR_
#undef SBAR_
#undef VMCNT4_
#undef STAGE_
#undef LDA_
#undef LDB_
#undef MFMA_

#pragma unroll
    for (int m = 0; m < 8; ++m)
#pragma unroll
        for (int n = 0; n < 4; ++n)
#pragma unroll
            for (int r = 0; r < 4; ++r) {
                int row = bm * 256 + wm * 128 + m * 16 + lq * 4 + r;
                int col = bn * 256 + wn * 64 + n * 16 + lr;
                float v = acc[m][n][r];
                if constexpr (std::is_same_v<OutT, short>)
                    C[(long)row * N + col] = f2bf(v);
                else
                    C[(long)row * N + col] = v;
            }
}

// ---------------- fast-weight: two-kernel decomposition ----------------
// fwA: per (b,h,mem) compute W_pre^T for chunks 1..3 (f32 accum, bf16 store).
// fwB: per (b,h,c) fully parallel output: O = (qk^T.mask) v + q W_pre, mix, store.
// XOR-swizzled LDS (verified R4 stage/read pair); W frags read global->regs.
#define SZF(row, col) (((row) << 6) + ((col) ^ (((row) & 7) << 3)))
#define LGKM0_() do { asm volatile("s_waitcnt lgkmcnt(0)" ::: "memory"); __builtin_amdgcn_sched_barrier(0); } while (0)

// phi (elu+1, row-normalize) in place; lane = row. Two-pass, no big arrays.
__device__ __forceinline__ void phi_lane(short* area, int lane) {
    v8s r[8];
#pragma unroll
    for (int g = 0; g < 8; g++)
        r[g] = *(const v8s*)&area[SZF(lane, g * 8)];
    float s = 0.f;
#pragma unroll
    for (int g = 0; g < 8; g++)
#pragma unroll
        for (int k = 0; k < 8; k++) {
            float x = bf2f(r[g][k]);
            s += x > 0.f ? x + 1.f : __expf(x);
        }
    float inv = 1.f / s;
#pragma unroll
    for (int g = 0; g < 8; g++) {
        v8s o;
#pragma unroll
        for (int k = 0; k < 8; k++) {
            float x = bf2f(r[g][k]);
            float e = x > 0.f ? x + 1.f : __expf(x);
            o[k] = f2bf(e * inv);
        }
        *(v8s*)&area[SZF(lane, g * 8)] = o;
    }
}

// in-place 64x64 transpose; lane = row
__device__ __forceinline__ void transpose_lane(short* area, int lane) {
    v8s r[8];
#pragma unroll
    for (int g = 0; g < 8; g++)
        r[g] = *(const v8s*)&area[SZF(lane, g * 8)];
    LGKM0_();
#pragma unroll
    for (int g = 0; g < 8; g++)
#pragma unroll
        for (int k = 0; k < 8; k++)
            area[SZF(g * 8 + k, lane)] = r[g][k];
}

__global__ void __launch_bounds__(64)
fwA(const short* __restrict__ qkv, short* __restrict__ wpre) {
    const int bid = blockIdx.x;                       // 2048 = 64b x 16h x 2mem
    const int b = bid & 63, h = (bid >> 6) & 15, mem = bid >> 10;
    const int lane = threadIdx.x;
    const int lq = lane >> 4, lr = lane & 15;
    __shared__ __align__(16) short Ak[4096];
    __shared__ __align__(16) short Av[4096];

    const int srow = lane >> 3;
    const int scolw = ((lane & 7) ^ (srow & 7)) << 3;
    const int koff = 64 + mem * 64;

    v4f wacc[4][4] = {};   // W^T state, f32

    for (int c = 0; c < 3; c++) {
        LGKM0_();   // prior iteration's LDS reads complete before overwrite
        {
            const short* g = qkv + ((long)((c * 64 + srow) * 64 + b)) * 4096 + h * 256 + koff + scolw;
#pragma unroll
            for (int i = 0; i < 8; i++)
                load_lds16(g + (long)i * 8 * 64 * 4096, Ak + i * 512);
        }
        {
            const short* g = qkv + ((long)((c * 64 + srow) * 64 + b)) * 4096 + h * 256 + 192 + scolw;
#pragma unroll
            for (int i = 0; i < 8; i++)
                load_lds16(g + (long)i * 8 * 64 * 4096, Av + i * 512);
        }
        asm volatile("s_waitcnt vmcnt(0)" ::: "memory");
        __builtin_amdgcn_sched_barrier(0);

        phi_lane(Ak, lane);
        transpose_lane(Av, lane);
        LGKM0_();

        v8s vf[4][2];
#pragma unroll
        for (int i = 0; i < 4; i++)
#pragma unroll
            for (int kk = 0; kk < 2; kk++)
                vf[i][kk] = *(const v8s*)&Av[SZF(16 * i + lr, 32 * kk + 8 * lq)];
        // W^T += v^T k   (ktb = rows of k^T = column gather from Ak)
#pragma unroll
        for (int n = 0; n < 4; n++) {
            v8s ktb[2];
#pragma unroll
            for (int kk = 0; kk < 2; kk++) {
                v8s t;
#pragma unroll
                for (int e = 0; e < 8; e++)
                    t[e] = Ak[SZF(32 * kk + 8 * lq + e, 16 * n + lr)];
                ktb[kk] = t;
            }
#pragma unroll
            for (int i = 0; i < 4; i++) {
                wacc[i][n] = __builtin_amdgcn_mfma_f32_16x16x32_bf16(vf[i][0], ktb[0], wacc[i][n], 0, 0, 0);
                wacc[i][n] = __builtin_amdgcn_mfma_f32_16x16x32_bf16(vf[i][1], ktb[1], wacc[i][n], 0, 0, 0);
            }
        }
        // store W_pre^T (row-major 64x64 bf16) for chunk c+1
        short* wp = wpre + (((long)(mem * 3 + c) * 16 + h) * 64 + b) * 4096;
#pragma unroll
        for (int i = 0; i < 4; i++)
#pragma unroll
            for (int n = 0; n < 4; n++)
#pragma unroll
                for (int r2 = 0; r2 < 4; r2++)
                    wp[(16 * i + lq * 4 + r2) * 64 + 16 * n + lr] = f2bf(wacc[i][n][r2]);
    }
}

__global__ void __launch_bounds__(256)
fwB(const short* __restrict__ qkv, const short* __restrict__ wpre,
    const float* __restrict__ pi0, short* __restrict__ outm) {
    const int bid = blockIdx.x;                       // 4096 = 64b x 16h x 4c
    const int b = bid & 63, h = (bid >> 6) & 15, c = bid >> 10;
    const int tid = threadIdx.x;
    const int wv = tid >> 6, lane = tid & 63;
    const int lq = lane >> 4, lr = lane & 15;
    __shared__ __align__(16) short sq[4096];
    __shared__ __align__(16) short sk1[4096];
    __shared__ __align__(16) short sk2[4096];
    __shared__ __align__(16) short svT[4096];

    const int srow = lane >> 3;
    const int scolw = ((lane & 7) ^ (srow & 7)) << 3;

    // wave wv stages mat wv (0=q,1=k1,2=k2,3=v)
    {
        short* area = (wv == 0) ? sq : (wv == 1) ? sk1 : (wv == 2) ? sk2 : svT;
        const short* g = qkv + ((long)((c * 64 + srow) * 64 + b)) * 4096 + h * 256 + wv * 64 + scolw;
#pragma unroll
        for (int i = 0; i < 8; i++)
            load_lds16(g + (long)i * 8 * 64 * 4096, area + i * 512);
    }
    asm volatile("s_waitcnt vmcnt(0)" ::: "memory");
    __syncthreads();

    if (wv == 0)      phi_lane(sq, lane);
    else if (wv == 1) phi_lane(sk1, lane);
    else if (wv == 2) phi_lane(sk2, lane);
    else              transpose_lane(svT, lane);
    __syncthreads();

    // q A-frags for this wave's 16-row slice
    v8s qa[2];
    qa[0] = *(const v8s*)&sq[SZF(16 * wv + lr, 8 * lq)];
    qa[1] = *(const v8s*)&sq[SZF(16 * wv + lr, 32 + 8 * lq)];

    // W_pre^T B-frags straight from global (c>0); issued early, land under S
    v8s wb1[4][2], wb2[4][2];
    if (c > 0) {
        const short* w1 = wpre + (((long)(0 * 3 + (c - 1)) * 16 + h) * 64 + b) * 4096;
        const short* w2 = wpre + (((long)(1 * 3 + (c - 1)) * 16 + h) * 64 + b) * 4096;
#pragma unroll
        for (int n = 0; n < 4; n++)
#pragma unroll
            for (int kk = 0; kk < 2; kk++) {
                wb1[n][kk] = *(const v8s*)&w1[(16 * n + lr) * 64 + 32 * kk + 8 * lq];
                wb2[n][kk] = *(const v8s*)&w2[(16 * n + lr) * 64 + 32 * kk + 8 * lq];
            }
    }
    float pv[4];
#pragma unroll
    for (int r2 = 0; r2 < 4; r2++) {
        float p = pi0[h * 256 + c * 64 + 16 * wv + lq * 4 + r2];
        pv[r2] = fminf(fmaxf(p, 0.f), 1.f);
    }

    // S1 = q k1^T, S2 = q k2^T  (rows 16wv)
    v4f sacc1[4], sacc2[4];
#pragma unroll
    for (int n = 0; n < 4; n++) {
        v8s b10 = *(const v8s*)&sk1[SZF(16 * n + lr, 8 * lq)];
        v8s b11 = *(const v8s*)&sk1[SZF(16 * n + lr, 32 + 8 * lq)];
        v8s b20 = *(const v8s*)&sk2[SZF(16 * n + lr, 8 * lq)];
        v8s b21 = *(const v8s*)&sk2[SZF(16 * n + lr, 32 + 8 * lq)];
        v4f t1 = {}, t2 = {};
        t1 = __builtin_amdgcn_mfma_f32_16x16x32_bf16(qa[0], b10, t1, 0, 0, 0);
        t2 = __builtin_amdgcn_mfma_f32_16x16x32_bf16(qa[0], b20, t2, 0, 0, 0);
        t1 = __builtin_amdgcn_mfma_f32_16x16x32_bf16(qa[1], b11, t1, 0, 0, 0);
        t2 = __builtin_amdgcn_mfma_f32_16x16x32_bf16(qa[1], b21, t2, 0, 0, 0);
        sacc1[n] = t1; sacc2[n] = t2;
    }
    __syncthreads();   // all k B-frag reads done; sk areas overwritable

    // masked S (bf16) -> own rows of sk areas
#pragma unroll
    for (int n = 0; n < 4; n++)
#pragma unroll
        for (int r2 = 0; r2 < 4; r2++) {
            int t_ = 16 * wv + lq * 4 + r2;
            int s_ = 16 * n + lr;
            sk1[SZF(t_, s_)] = f2bf(s_ <= t_ ? sacc1[n][r2] : 0.f);
            sk2[SZF(t_, s_)] = f2bf(s_ <= t_ ? sacc2[n][r2] : 0.f);
        }
    LGKM0_();   // own-wave S writes before own-row frag reads

    v8s sa1[2], sa2[2];
    sa1[0] = *(const v8s*)&sk1[SZF(16 * wv + lr, 8 * lq)];
    sa1[1] = *(const v8s*)&sk1[SZF(16 * wv + lr, 32 + 8 * lq)];
    sa2[0] = *(const v8s*)&sk2[SZF(16 * wv + lr, 8 * lq)];
    sa2[1] = *(const v8s*)&sk2[SZF(16 * wv + lr, 32 + 8 * lq)];

    // O = S v + q W_pre ; f32 mix ; store
#pragma unroll
    for (int j = 0; j < 4; j++) {
        v8s vb0 = *(const v8s*)&svT[SZF(16 * j + lr, 8 * lq)];
        v8s vb1 = *(const v8s*)&svT[SZF(16 * j + lr, 32 + 8 * lq)];
        v4f t1 = {}, t2 = {};
        t1 = __builtin_amdgcn_mfma_f32_16x16x32_bf16(sa1[0], vb0, t1, 0, 0, 0);
        t2 = __builtin_amdgcn_mfma_f32_16x16x32_bf16(sa2[0], vb0, t2, 0, 0, 0);
        t1 = __builtin_amdgcn_mfma_f32_16x16x32_bf16(sa1[1], vb1, t1, 0, 0, 0);
        t2 = __builtin_amdgcn_mfma_f32_16x16x32_bf16(sa2[1], vb1, t2, 0, 0, 0);
        if (c > 0) {
            t1 = __builtin_amdgcn_mfma_f32_16x16x32_bf16(qa[0], wb1[j][0], t1, 0, 0, 0);
            t2 = __builtin_amdgcn_mfma_f32_16x16x32_bf16(qa[0], wb2[j][0], t2, 0, 0, 0);
            t1 = __builtin_amdgcn_mfma_f32_16x16x32_bf16(qa[1], wb1[j][1], t1, 0, 0, 0);
            t2 = __builtin_amdgcn_mfma_f32_16x16x32_bf16(qa[1], wb2[j][1], t2, 0, 0, 0);
        }
#pragma unroll
        for (int r2 = 0; r2 < 4; r2++) {
            int t_ = 16 * wv + lq * 4 + r2;
            float val = 0.125f * (pv[r2] * t1[r2] + (1.f - pv[r2]) * t2[r2]);
            outm[((long)((c * 64 + t_) * 64 + b)) * 1024 + h * 64 + 16 * j + lr] = f2bf(val);
        }
    }
}

// ---------------- residual + LayerNorm over DM=1024 ----------------
__global__ void __launch_bounds__(256)
ln_kernel(const float* __restrict__ h, const float* __restrict__ attn,
          const float* __restrict__ gamma, const float* __restrict__ beta,
          float* __restrict__ out) {
    const int row = blockIdx.x;
    const long base = (long)row * 1024;
    const int tid = threadIdx.x;
    float4 xh = ((const float4*)(h + base))[tid];
    float4 xa = ((const float4*)(attn + base))[tid];
    float4 x;
    x.x = xh.x + xa.x; x.y = xh.y + xa.y; x.z = xh.z + xa.z; x.w = xh.w + xa.w;
    float s = x.x + x.y + x.z + x.w;
    float s2 = x.x * x.x + x.y * x.y + x.z * x.z + x.w * x.w;
#pragma unroll
    for (int m = 32; m > 0; m >>= 1) {
        s += __shfl_xor(s, m, 64);
        s2 += __shfl_xor(s2, m, 64);
    }
    __shared__ float ps[4], ps2[4];
    int w = tid >> 6, lane = tid & 63;
    if (lane == 0) { ps[w] = s; ps2[w] = s2; }
    __syncthreads();
    s = ps[0] + ps[1] + ps[2] + ps[3];
    s2 = ps2[0] + ps2[1] + ps2[2] + ps2[3];
    float mu = s * (1.f / 1024.f);
    float var = s2 * (1.f / 1024.f) - mu * mu;
    float inv = rsqrtf(var + 1e-5f);
    float4 g = ((const float4*)gamma)[tid];
    float4 bb = ((const float4*)beta)[tid];
    float4 o;
    o.x = (x.x - mu) * inv * g.x + bb.x;
    o.y = (x.y - mu) * inv * g.y + bb.y;
    o.z = (x.z - mu) * inv * g.z + bb.z;
    o.w = (x.w - mu) * inv * g.w + bb.w;
    ((float4*)(out + base))[tid] = o;
}

extern "C" void kernel_launch(void* const* d_in, const int* in_sizes, int n_in,
                              void* d_out, int out_size, void* d_ws, size_t ws_size,
                              hipStream_t stream) {
    const float* h     = (const float*)d_in[0];
    const float* qkvw  = (const float*)d_in[1];
    const float* ow    = (const float*)d_in[2];
    const float* gamma = (const float*)d_in[3];
    const float* beta  = (const float*)d_in[4];
    const float* pi0   = (const float*)d_in[5];
    float* out = (float*)d_out;
    char* ws = (char*)d_ws;

    short* h_bf   = (short*)(ws);                 // 32MB; reused later as lmix
    short* wq_bf  = (short*)(ws + 33554432);      // 8MB
    short* wo_bf  = (short*)(ws + 41943040);      // 2MB
    short* qkv_bf = (short*)(ws + 44040192);      // 128MB; reused later as attn f32 (64MB)
    short* wpre   = (short*)(ws + 178257920);     // 50.3MB W_pre buffer
    float* attnf  = (float*)(ws + 44040192);
    short* lmix   = h_bf;

    cvt_bf16<<<16384, 256, 0, stream>>>(h, h_bf, 16777216 / 4);
    cvt_bf16<<<4096, 256, 0, stream>>>(qkvw, wq_bf, 4194304 / 4);
    cvt_bf16<<<1024, 256, 0, stream>>>(ow, wo_bf, 1048576 / 4);

    gemm_nt<short><<<dim3(64, 16), 512, 0, stream>>>(h_bf, wq_bf, qkv_bf, 16384, 4096, 1024);

    fwA<<<2048, 64, 0, stream>>>(qkv_bf, wpre);
    fwB<<<4096, 256, 0, stream>>>(qkv_bf, wpre, pi0, lmix);

    gemm_nt<float><<<dim3(64, 4), 512, 0, stream>>>(lmix, wo_bf, attnf, 16384, 1024, 1024);

    ln_kernel<<<16384, 256, 0, stream>>>(h, attnf, gamma, beta, out);
}